// Round 8
// baseline (264.332 us; speedup 1.0000x reference)
//
#include <hip/hip_runtime.h>

#define NB 8
#define NH 56
#define NW 56
#define NHW 3136          // NH*NW
#define NCHW 802816
#define NPIX 25088        // NB*NHW
#define NHP 58            // padded dim
#define EPSV 1e-5f

typedef float f32x4 __attribute__((ext_vector_type(4)));
typedef __bf16 bf16x8 __attribute__((ext_vector_type(8)));

__device__ __forceinline__ unsigned short f2b(float f) {   // RNE
  unsigned int u = __float_as_uint(f);
  u += 0x7FFFu + ((u >> 16) & 1u);
  return (unsigned short)(u >> 16);
}
__device__ __forceinline__ float blo(unsigned int u){ return __uint_as_float(u << 16); }
__device__ __forceinline__ float bhi(unsigned int u){ return __uint_as_float(u & 0xFFFF0000u); }
__device__ __forceinline__ unsigned int pack_trunc(float f0, float f1) {
  return __builtin_amdgcn_perm(__float_as_uint(f1), __float_as_uint(f0), 0x07060302u);
}
__device__ __forceinline__ bf16x8 asbf(const uint4& q) { return *(const bf16x8*)&q; }

// ---------------------------------------------------------------------------
// P0: zero 1px borders of xbp and t1b
// ---------------------------------------------------------------------------
__global__ __launch_bounds__(256) void clear_borders(
    unsigned short* __restrict__ xbp, unsigned short* __restrict__ t1b)
{
  int i = blockIdx.x*256 + threadIdx.x;        // 58368 exact
  int q = i & 31; int pid = i >> 5;
  int b = pid / 228, j = pid % 228;
  int y, x;
  if (j < 58)       { y = 0;  x = j; }
  else if (j < 116) { y = 57; x = j - 58; }
  else { int jj = j - 116; y = 1 + (jj >> 1); x = (jj & 1) * 57; }
  size_t addr = ((size_t)(b*NHP + y)*NHP + x)*256 + q*8;
  uint4 z = make_uint4(0u,0u,0u,0u);
  *(uint4*)(xbp + addr) = z;
  *(uint4*)(t1b + addr) = z;
}

// ---------------------------------------------------------------------------
// P1: x NCHW fp32 -> xbp padded NHWC bf16 (interior)
// ---------------------------------------------------------------------------
__global__ __launch_bounds__(256) void prep_x(
    const float* __restrict__ x, unsigned short* __restrict__ xbp)
{
  __shared__ float T[64][65];
  const int pxt  = blockIdx.x * 64;
  const int cg   = blockIdx.y * 64;
  const int b    = pxt / NHW;
  const int rem0 = pxt % NHW;
  const int t    = threadIdx.x;
  const int pl   = t & 63;
  const int c0   = t >> 6;
  const float* src = x + (size_t)b*NCHW + rem0;
  #pragma unroll
  for (int it = 0; it < 16; ++it) {
    int c = c0 + it*4;
    T[c][pl] = src[(size_t)(cg + c)*NHW + pl];
  }
  __syncthreads();
  const int pr = t >> 5;
  const int cp = t & 31;
  #pragma unroll
  for (int it = 0; it < 8; ++it) {
    int pxl = pr + it*8;
    int rem = rem0 + pxl;
    int ho = rem / NW, wo = rem % NW;
    unsigned int pk = ((unsigned int)f2b(T[cp*2+1][pxl]) << 16) | (unsigned int)f2b(T[cp*2][pxl]);
    *(unsigned int*)(xbp + ((size_t)(b*NHP + ho + 1)*NHP + (wo + 1))*256 + cg + cp*2) = pk;
  }
}

// ---------------------------------------------------------------------------
// P2: w [co][ci][3][3] fp32 -> wq [r=36][kc=8][n=256][8] bf16 (frag-direct)
// round r covers ktap=r>>2, ci in [(r&3)*64, +64); chunk kc -> ci_local kc*8+j
// ---------------------------------------------------------------------------
__global__ __launch_bounds__(256) void prep_wq(
    const float* __restrict__ w, unsigned short* __restrict__ wq)
{
  int i = blockIdx.x*256 + threadIdx.x;    // 589824 exact
  int j  = i & 7;
  int n  = (i >> 3) & 255;
  int kc = (i >> 11) & 7;
  int r  = i >> 14;
  int ktap = r >> 2, cic = r & 3;
  int ci = cic*64 + kc*8 + j;
  wq[i] = f2b(w[((size_t)n*256 + ci)*9 + ktap]);
}

// P3: off_w -> wq3 [r=36][kc=8][n=32][8] bf16, n>=18 zero
__global__ __launch_bounds__(256) void prep_wq3(
    const float* __restrict__ ow, unsigned short* __restrict__ wq)
{
  int i = blockIdx.x*256 + threadIdx.x;    // 73728 exact
  int j  = i & 7;
  int n  = (i >> 3) & 31;
  int kc = (i >> 8) & 7;
  int r  = i >> 11;
  int ktap = r >> 2, cic = r & 3;
  int ci = cic*64 + kc*8 + j;
  wq[i] = (n < 18) ? f2b(ow[((size_t)n*256 + ci)*9 + ktap]) : (unsigned short)0;
}

__device__ __forceinline__ int tapoff(int r) {
  int k = r >> 2, cic = r & 3;
  int ky = k/3, kx = k - ky*3;
  return (ky*NHP + kx)*256 + cic*64;
}

// ---------------------------------------------------------------------------
// GEMM1: conv3x3 + BN + ReLU -> t1b padded NHWC bf16
// BM=64 BN=256 BK=64, 512 thr = 8 waves (2M x 4N), wave 32x64; grid 392
// A: LDS double-buffer, 1 barrier/round.  B: direct global frag loads (wq).
// ---------------------------------------------------------------------------
__global__ __launch_bounds__(512, 4) void gemm_conv1(
    const unsigned short* __restrict__ xbp, const unsigned short* __restrict__ w1q,
    const float* __restrict__ gam, const float* __restrict__ bet,
    const float* __restrict__ mu,  const float* __restrict__ var,
    unsigned short* __restrict__ t1b)
{
  __shared__ unsigned short SMEM[18432];   // Al dbuf 2x4096 | epilogue bounce 8x2304
  unsigned short* Al = SMEM;

  const int m0   = blockIdx.x * 64;
  const int t    = threadIdx.x;
  const int lane = t & 63;
  const int wv   = t >> 6;
  const int wvM  = wv & 1;
  const int wvN  = wv >> 1;
  const int quad = lane >> 4;
  const int l15  = lane & 15;

  const int srow = t >> 3, seg = t & 7, sxor = srow & 7;
  const int px = m0 + srow;
  const int b = px / NHW, rem = px % NHW;
  const int ho = rem / NW, wo = rem % NW;
  const unsigned int pbase = ((unsigned int)(b*NHP + ho)*NHP + wo)*256u + seg*8u;

  // B frag base: lane column = wvN*64 + nt*16 + l15
  const unsigned short* bqb = w1q + (size_t)(wvN*64 + l15)*8;
#define BQ1(R,KK,NT) (const uint4*)(bqb + ((size_t)(((R)*8 + (KK)*4 + quad))*256 + (NT)*16)*8)

  f32x4 acc[2][4];
  #pragma unroll
  for (int i = 0; i < 2; ++i)
    #pragma unroll
    for (int j = 0; j < 4; ++j) acc[i][j] = (f32x4)(0.f);

  uint4 pb0[4];
  {   // prologue: A for r=0 into buf0; B kk0 frags for r=0
    uint4 pA = *(const uint4*)(xbp + pbase + tapoff(0));
    #pragma unroll
    for (int nt = 0; nt < 4; ++nt) pb0[nt] = *BQ1(0,0,nt);
    *(uint4*)(&Al[srow*64 + ((seg ^ sxor)*8)]) = pA;
    __syncthreads();
  }

  for (int r = 0; r < 36; ++r) {
    const int cur = (r & 1) * 4096;
    const int nxt = 4096 - cur;
    const int rn  = (r < 35) ? r + 1 : 35;
    uint4 pAn = *(const uint4*)(xbp + pbase + tapoff(rn));
    uint4 pb1[4];
    #pragma unroll
    for (int nt = 0; nt < 4; ++nt) pb1[nt] = *BQ1(r,1,nt);
    __builtin_amdgcn_sched_barrier(0);
    // kk = 0 (B from pb0, prefetched last round)
    {
      const int s8 = quad ^ (l15 & 7);
      bf16x8 af0 = *(const bf16x8*)(&Al[cur + (wvM*32 +      l15)*64 + s8*8]);
      bf16x8 af1 = *(const bf16x8*)(&Al[cur + (wvM*32 + 16 + l15)*64 + s8*8]);
      #pragma unroll
      for (int nt = 0; nt < 4; ++nt) {
        bf16x8 bv = asbf(pb0[nt]);
        acc[0][nt] = __builtin_amdgcn_mfma_f32_16x16x32_bf16(af0, bv, acc[0][nt], 0, 0, 0);
        acc[1][nt] = __builtin_amdgcn_mfma_f32_16x16x32_bf16(af1, bv, acc[1][nt], 0, 0, 0);
      }
    }
    #pragma unroll
    for (int nt = 0; nt < 4; ++nt) pb0[nt] = *BQ1(rn,0,nt);   // next-round kk0
    __builtin_amdgcn_sched_barrier(0);
    // kk = 1
    {
      const int s8 = (4 + quad) ^ (l15 & 7);
      bf16x8 af0 = *(const bf16x8*)(&Al[cur + (wvM*32 +      l15)*64 + s8*8]);
      bf16x8 af1 = *(const bf16x8*)(&Al[cur + (wvM*32 + 16 + l15)*64 + s8*8]);
      #pragma unroll
      for (int nt = 0; nt < 4; ++nt) {
        bf16x8 bv = asbf(pb1[nt]);
        acc[0][nt] = __builtin_amdgcn_mfma_f32_16x16x32_bf16(af0, bv, acc[0][nt], 0, 0, 0);
        acc[1][nt] = __builtin_amdgcn_mfma_f32_16x16x32_bf16(af1, bv, acc[1][nt], 0, 0, 0);
      }
    }
    *(uint4*)(&Al[nxt + srow*64 + ((seg ^ sxor)*8)]) = pAn;   // A for r+1
    __syncthreads();
  }
#undef BQ1

  // epilogue: BN+ReLU -> per-wave bounce (32px x 72 shorts) -> padded t1b
  unsigned short* Sw = SMEM + wv*2304;
  #pragma unroll
  for (int nt = 0; nt < 4; ++nt) {
    const int co = wvN*64 + nt*16 + l15;
    const float inv  = gam[co] * rsqrtf(var[co] + EPSV);
    const float beta = bet[co] - mu[co]*inv;
    #pragma unroll
    for (int mt = 0; mt < 2; ++mt) {
      #pragma unroll
      for (int rr = 0; rr < 4; ++rr) {
        const int pxl = mt*16 + quad*4 + rr;
        float val = acc[mt][nt][rr]*inv + beta;
        val = val > 0.f ? val : 0.f;
        Sw[pxl*72 + nt*16 + l15] = f2b(val);
      }
    }
  }
  __builtin_amdgcn_s_waitcnt(0xC07F);   // lgkmcnt(0)
  __builtin_amdgcn_s_barrier();
  #pragma unroll
  for (int i = 0; i < 4; ++i) {
    const int pxl = (lane >> 3) + 8*i;
    const int sc  = lane & 7;
    uint4 q = *(const uint4*)(&Sw[pxl*72 + sc*8]);
    const int pg = m0 + wvM*32 + pxl;
    const int bb = pg / NHW, rm = pg % NHW;
    const int hh = rm / NW, ww = rm % NW;
    *(uint4*)(t1b + ((size_t)(bb*NHP + hh + 1)*NHP + ww + 1)*256 + wvN*64 + sc*8) = q;
  }
}

// ---------------------------------------------------------------------------
// GEMM-OFF: offset conv, split-K x4, atomicAdd into toff (pre-zeroed)
// BM=64 BN=32, 256 thr = 4 waves (wave 16x32); grid (392,4)
// ---------------------------------------------------------------------------
__global__ __launch_bounds__(256, 6) void gemm_off(
    const unsigned short* __restrict__ t1b, const unsigned short* __restrict__ w3q,
    const float* __restrict__ ob, float* __restrict__ toff)
{
  __shared__ unsigned short Al[2*4096];

  const int m0 = blockIdx.x * 64;
  const int kc = blockIdx.y;
  const int t    = threadIdx.x;
  const int lane = t & 63;
  const int wv   = t >> 6;
  const int quad = lane >> 4;
  const int l15  = lane & 15;

  const int arow = t >> 2, as4 = t & 3, axor = arow & 7;
  const int pxa = m0 + arow;
  const int ba = pxa / NHW, rema = pxa % NHW;
  const unsigned int pbase = ((unsigned int)(ba*NHP + rema/NW)*NHP + rema%NW)*256u;

  const unsigned short* bqb = w3q + (size_t)l15*8;
#define BQ3(R,KK,NT) (const uint4*)(bqb + ((size_t)(((R)*8 + (KK)*4 + quad))*32 + (NT)*16)*8)

  f32x4 acc[2];
  #pragma unroll
  for (int nt = 0; nt < 2; ++nt) {
    float init = 0.f;
    if (kc == 0) { int co = nt*16 + l15; init = (co < 18) ? ob[co] : 0.f; }
    acc[nt] = (f32x4)(init);
  }

  uint4 pb0[2];
  {
    const int r0 = kc*9;
    uint4 pA0 = *(const uint4*)(t1b + pbase + tapoff(r0) + as4*8);
    uint4 pA1 = *(const uint4*)(t1b + pbase + tapoff(r0) + (as4+4)*8);
    #pragma unroll
    for (int nt = 0; nt < 2; ++nt) pb0[nt] = *BQ3(r0,0,nt);
    *(uint4*)(&Al[arow*64 + ((as4     ^ axor)*8)]) = pA0;
    *(uint4*)(&Al[arow*64 + (((as4+4) ^ axor)*8)]) = pA1;
    __syncthreads();
  }

  for (int rr = 0; rr < 9; ++rr) {
    const int r   = kc*9 + rr;
    const int cur = (rr & 1) * 4096;
    const int nxt = 4096 - cur;
    const int rn  = (rr < 8) ? r + 1 : r;
    uint4 pA0 = *(const uint4*)(t1b + pbase + tapoff(rn) + as4*8);
    uint4 pA1 = *(const uint4*)(t1b + pbase + tapoff(rn) + (as4+4)*8);
    uint4 pb1[2];
    #pragma unroll
    for (int nt = 0; nt < 2; ++nt) pb1[nt] = *BQ3(r,1,nt);
    __builtin_amdgcn_sched_barrier(0);
    {
      const int s8 = quad ^ (l15 & 7);
      bf16x8 af = *(const bf16x8*)(&Al[cur + (wv*16 + l15)*64 + s8*8]);
      #pragma unroll
      for (int nt = 0; nt < 2; ++nt)
        acc[nt] = __builtin_amdgcn_mfma_f32_16x16x32_bf16(af, asbf(pb0[nt]), acc[nt], 0, 0, 0);
    }
    #pragma unroll
    for (int nt = 0; nt < 2; ++nt) pb0[nt] = *BQ3(rn,0,nt);
    __builtin_amdgcn_sched_barrier(0);
    {
      const int s8 = (4 + quad) ^ (l15 & 7);
      bf16x8 af = *(const bf16x8*)(&Al[cur + (wv*16 + l15)*64 + s8*8]);
      #pragma unroll
      for (int nt = 0; nt < 2; ++nt)
        acc[nt] = __builtin_amdgcn_mfma_f32_16x16x32_bf16(af, asbf(pb1[nt]), acc[nt], 0, 0, 0);
    }
    *(uint4*)(&Al[nxt + arow*64 + ((as4     ^ axor)*8)]) = pA0;
    *(uint4*)(&Al[nxt + arow*64 + (((as4+4) ^ axor)*8)]) = pA1;
    __syncthreads();
  }
#undef BQ3

  #pragma unroll
  for (int nt = 0; nt < 2; ++nt) {
    const int co = nt*16 + l15;
    if (co < 18) {
      #pragma unroll
      for (int rr2 = 0; rr2 < 4; ++rr2) {
        const int pg = m0 + wv*16 + quad*4 + rr2;
        const int bb = pg / NHW, rm = pg % NHW;
        atomicAdd(&toff[(size_t)bb*(18*NHW) + (size_t)co*NHW + rm], acc[nt][rr2]);
      }
    }
  }
}

// ---------------------------------------------------------------------------
// GEMM2: deform_conv + BN + residual + ReLU -> out NCHW fp32
// BM=64 BN=256 BK=64, 512 thr; A dbuf 1-barrier, B direct frags, maskless bilinear
// ---------------------------------------------------------------------------
__global__ __launch_bounds__(512, 4) void gemm_deform(
    const unsigned short* __restrict__ t1b, const unsigned short* __restrict__ w2q,
    const float* __restrict__ toff, const float* __restrict__ xres,
    const float* __restrict__ gam, const float* __restrict__ bet,
    const float* __restrict__ mu,  const float* __restrict__ var,
    float* __restrict__ outp)
{
  __shared__ float SMEMF[8448];            // Al dbuf 16KB | epilogue 33.8KB
  unsigned short* Al = (unsigned short*)SMEMF;

  const int m0   = blockIdx.x * 64;
  const int t    = threadIdx.x;
  const int lane = t & 63;
  const int wv   = t >> 6;
  const int wvM  = wv & 1;
  const int wvN  = wv >> 1;
  const int quad = lane >> 4;
  const int l15  = lane & 15;

  const int srow = t >> 3, seg = t & 7, sxor = srow & 7;
  const int px = m0 + srow;
  const int b = px / NHW, rem = px % NHW;
  const int ho = rem / NW, wo = rem % NW;
  const int obb = b*(18*NHW) + rem;
  const unsigned int prowb = (unsigned int)(b*NHP);

  const unsigned short* bqb = w2q + (size_t)(wvN*64 + l15)*8;
#define BQ2(R,KK,NT) (const uint4*)(bqb + ((size_t)(((R)*8 + (KK)*4 + quad))*256 + (NT)*16)*8)

  f32x4 acc[2][4];
  #pragma unroll
  for (int i = 0; i < 2; ++i)
    #pragma unroll
    for (int j = 0; j < 4; ++j) acc[i][j] = (f32x4)(0.f);

  unsigned int o00, o01, o10, o11;
  float w00, w01, w10, w11;
#define COORDS(KK) {                                                   \
    const int ky_ = (KK)/3, kx_ = (KK) - ky_*3;                        \
    const float offy = toff[obb + (KK)*NHW];                           \
    const float offx = toff[obb + (9+(KK))*NHW];                       \
    const float yf = (float)(ho - 1 + ky_) + offy;                     \
    const float xf = (float)(wo - 1 + kx_) + offx;                     \
    const float y0f = floorf(yf), x0f = floorf(xf);                    \
    const float ty = yf - y0f,   tx = xf - x0f;                        \
    const int y0p = (int)y0f + 1, x0p = (int)x0f + 1;                  \
    const int cy0 = min(max(y0p,   0), NHP-1);                         \
    const int cy1 = min(max(y0p+1, 0), NHP-1);                         \
    const int cx0 = min(max(x0p,   0), NHP-1);                         \
    const int cx1 = min(max(x0p+1, 0), NHP-1);                         \
    w00 = (1.f-ty)*(1.f-tx);  w01 = (1.f-ty)*tx;                       \
    w10 = ty*(1.f-tx);        w11 = ty*tx;                             \
    o00 = ((prowb + cy0)*NHP + cx0)*256u + seg*8u;                     \
    o01 = ((prowb + cy0)*NHP + cx1)*256u + seg*8u;                     \
    o10 = ((prowb + cy1)*NHP + cx0)*256u + seg*8u;                     \
    o11 = ((prowb + cy1)*NHP + cx1)*256u + seg*8u;                     \
  }
#define BILIN(RES, C00, C01, C10, C11) {                                             \
    uint4 res_;                                                                      \
    { float a0 = w00*blo(C00.x)+w01*blo(C01.x)+w10*blo(C10.x)+w11*blo(C11.x);        \
      float a1 = w00*bhi(C00.x)+w01*bhi(C01.x)+w10*bhi(C10.x)+w11*bhi(C11.x);        \
      res_.x = pack_trunc(a0, a1); }                                                 \
    { float a0 = w00*blo(C00.y)+w01*blo(C01.y)+w10*blo(C10.y)+w11*blo(C11.y);        \
      float a1 = w00*bhi(C00.y)+w01*bhi(C01.y)+w10*bhi(C10.y)+w11*bhi(C11.y);        \
      res_.y = pack_trunc(a0, a1); }                                                 \
    { float a0 = w00*blo(C00.z)+w01*blo(C01.z)+w10*blo(C10.z)+w11*blo(C11.z);        \
      float a1 = w00*bhi(C00.z)+w01*bhi(C01.z)+w10*bhi(C10.z)+w11*bhi(C11.z);        \
      res_.z = pack_trunc(a0, a1); }                                                 \
    { float a0 = w00*blo(C00.w)+w01*blo(C01.w)+w10*blo(C10.w)+w11*blo(C11.w);        \
      float a1 = w00*bhi(C00.w)+w01*bhi(C01.w)+w10*bhi(C10.w)+w11*bhi(C11.w);        \
      res_.w = pack_trunc(a0, a1); }                                                 \
    RES = res_;                                                                      \
  }

  uint4 pb0[4];
  {   // prologue: bilinear A(r=0) -> buf0; B kk0 frags r=0
    COORDS(0);
    uint4 c00 = *(const uint4*)(t1b + o00);
    uint4 c01 = *(const uint4*)(t1b + o01);
    uint4 c10 = *(const uint4*)(t1b + o10);
    uint4 c11 = *(const uint4*)(t1b + o11);
    #pragma unroll
    for (int nt = 0; nt < 4; ++nt) pb0[nt] = *BQ2(0,0,nt);
    uint4 res; BILIN(res, c00, c01, c10, c11);
    *(uint4*)(&Al[srow*64 + ((seg ^ sxor)*8)]) = res;
    __syncthreads();
  }

  for (int r = 0; r < 36; ++r) {
    const int cur = (r & 1) * 4096;
    const int nxt = 4096 - cur;
    const int rn  = (r < 35) ? r + 1 : 35;
    if ((r & 3) == 3 && r < 35) COORDS((r+1) >> 2);
    const unsigned int cioN = (unsigned int)((rn & 3)*64);
    uint4 c00 = *(const uint4*)(t1b + o00 + cioN);
    uint4 c01 = *(const uint4*)(t1b + o01 + cioN);
    uint4 c10 = *(const uint4*)(t1b + o10 + cioN);
    uint4 c11 = *(const uint4*)(t1b + o11 + cioN);
    uint4 pb1[4];
    #pragma unroll
    for (int nt = 0; nt < 4; ++nt) pb1[nt] = *BQ2(r,1,nt);
    __builtin_amdgcn_sched_barrier(0);
    // kk = 0 (pb0 prefetched last round)
    {
      const int s8 = quad ^ (l15 & 7);
      bf16x8 af0 = *(const bf16x8*)(&Al[cur + (wvM*32 +      l15)*64 + s8*8]);
      bf16x8 af1 = *(const bf16x8*)(&Al[cur + (wvM*32 + 16 + l15)*64 + s8*8]);
      #pragma unroll
      for (int nt = 0; nt < 4; ++nt) {
        bf16x8 bv = asbf(pb0[nt]);
        acc[0][nt] = __builtin_amdgcn_mfma_f32_16x16x32_bf16(af0, bv, acc[0][nt], 0, 0, 0);
        acc[1][nt] = __builtin_amdgcn_mfma_f32_16x16x32_bf16(af1, bv, acc[1][nt], 0, 0, 0);
      }
    }
    #pragma unroll
    for (int nt = 0; nt < 4; ++nt) pb0[nt] = *BQ2(rn,0,nt);
    __builtin_amdgcn_sched_barrier(0);
    // kk = 1
    {
      const int s8 = (4 + quad) ^ (l15 & 7);
      bf16x8 af0 = *(const bf16x8*)(&Al[cur + (wvM*32 +      l15)*64 + s8*8]);
      bf16x8 af1 = *(const bf16x8*)(&Al[cur + (wvM*32 + 16 + l15)*64 + s8*8]);
      #pragma unroll
      for (int nt = 0; nt < 4; ++nt) {
        bf16x8 bv = asbf(pb1[nt]);
        acc[0][nt] = __builtin_amdgcn_mfma_f32_16x16x32_bf16(af0, bv, acc[0][nt], 0, 0, 0);
        acc[1][nt] = __builtin_amdgcn_mfma_f32_16x16x32_bf16(af1, bv, acc[1][nt], 0, 0, 0);
      }
    }
    {   // bilinear for r+1 -> other buffer
      uint4 res; BILIN(res, c00, c01, c10, c11);
      *(uint4*)(&Al[nxt + srow*64 + ((seg ^ sxor)*8)]) = res;
    }
    __syncthreads();
  }
#undef BQ2
#undef COORDS
#undef BILIN

  // epilogue: per-wave f32 bounce (32px x 33), 2 co-halves -> coalesced NCHW
  float* Sl = SMEMF + wv*1056;
  const int pxl_r = lane & 31;
  const int csel  = lane >> 5;
  const int pg    = m0 + wvM*32 + pxl_r;
  const int bo    = pg / NHW, remo = pg % NHW;
  const size_t obase = (size_t)bo*NCHW + remo;
  #pragma unroll
  for (int h = 0; h < 2; ++h) {
    __syncthreads();
    #pragma unroll
    for (int nt2 = 0; nt2 < 2; ++nt2) {
      const int nt = h*2 + nt2;
      #pragma unroll
      for (int mt = 0; mt < 2; ++mt) {
        #pragma unroll
        for (int rr = 0; rr < 4; ++rr) {
          const int pxl = mt*16 + quad*4 + rr;
          Sl[pxl*33 + nt2*16 + l15] = acc[mt][nt][rr];
        }
      }
    }
    __builtin_amdgcn_s_waitcnt(0xC07F);
    __builtin_amdgcn_s_barrier();
    #pragma unroll
    for (int j = 0; j < 16; ++j) {
      const int col = csel*16 + j;
      const int co  = wvN*64 + h*32 + col;
      const float inv  = gam[co] * rsqrtf(var[co] + EPSV);
      const float beta = bet[co] - mu[co]*inv;
      const size_t off = obase + (size_t)co*NHW;
      float val = Sl[pxl_r*33 + col];
      float o = val*inv + beta + xres[off];
      outp[off] = o > 0.f ? o : 0.f;
    }
  }
}

extern "C" void kernel_launch(void* const* d_in, const int* in_sizes, int n_in,
                              void* d_out, int out_size, void* d_ws, size_t ws_size,
                              hipStream_t stream) {
  const float* x   = (const float*)d_in[0];
  const float* w1  = (const float*)d_in[1];
  const float* g1  = (const float*)d_in[2];
  const float* b1  = (const float*)d_in[3];
  const float* m1  = (const float*)d_in[4];
  const float* v1  = (const float*)d_in[5];
  const float* ow  = (const float*)d_in[6];
  const float* ob  = (const float*)d_in[7];
  const float* w2  = (const float*)d_in[8];
  const float* g2  = (const float*)d_in[9];
  const float* b2  = (const float*)d_in[10];
  const float* m2  = (const float*)d_in[11];
  const float* v2  = (const float*)d_in[12];
  float* out = (float*)d_out;

  const size_t PADSZ = (size_t)NB*NHP*NHP*256;
  unsigned short* xbp = (unsigned short*)d_ws;
  unsigned short* t1b = xbp + PADSZ;
  float*          tof = (float*)(t1b + PADSZ);
  unsigned short* w1q = (unsigned short*)(tof + (size_t)NB*18*NHW);
  unsigned short* w2q = w1q + (size_t)589824;
  unsigned short* w3q = w2q + (size_t)589824;

  clear_borders<<<228, 256, 0, stream>>>(xbp, t1b);
  dim3 gp(392, 4, 1);
  prep_x<<<gp, 256, 0, stream>>>(x, xbp);
  prep_wq<<<2304, 256, 0, stream>>>(w1, w1q);
  prep_wq<<<2304, 256, 0, stream>>>(w2, w2q);
  prep_wq3<<<288, 256, 0, stream>>>(ow, w3q);
  hipMemsetAsync(tof, 0, (size_t)NB*18*NHW*sizeof(float), stream);

  gemm_conv1<<<392, 512, 0, stream>>>(xbp, w1q, g1, b1, m1, v1, t1b);
  dim3 go(392, 4, 1);
  gemm_off<<<go, 256, 0, stream>>>(t1b, w3q, ob, tof);
  gemm_deform<<<392, 512, 0, stream>>>(t1b, w2q, tof, x, g2, b2, m2, v2, out);
}